// Round 3
// baseline (526.511 us; speedup 1.0000x reference)
//
#include <hip/hip_runtime.h>

#define NN 50000
#define DIM 128
#define NREL 4
#define NEDGE 200000
#define NLAYER 3
#define SNB 196  // ceil(NN/256)
#define NODES_PER_BLK 8

typedef short s16x8 __attribute__((ext_vector_type(8)));
typedef float f32x4 __attribute__((ext_vector_type(4)));

__device__ __forceinline__ unsigned short f2bf(float f) {
    union { float f; unsigned u; } c; c.f = f;
    unsigned u = c.u + 0x7fffu + ((c.u >> 16) & 1u);
    return (unsigned short)(u >> 16);
}
__device__ __forceinline__ float lo_bf(unsigned u) {
    union { float f; unsigned u; } c; c.u = u << 16; return c.f;
}
__device__ __forceinline__ float hi_bf(unsigned u) {
    union { float f; unsigned u; } c; c.u = u & 0xffff0000u; return c.f;
}

// ---------------- diagnostics ----------------
__global__ __launch_bounds__(256) void k_constf(float* __restrict__ out, int n, float v) {
    int i = blockIdx.x * 256 + threadIdx.x;
    if (i < n) out[i] = v;
}

// ---------------- CSR build ----------------
__global__ __launch_bounds__(256) void k_count(const int* __restrict__ dst, int* __restrict__ counts) {
    int r = blockIdx.y;
    int i = blockIdx.x * 256 + threadIdx.x;
    if (i < NEDGE) {
        int d = dst[r * NEDGE + i];
        if ((unsigned)d < NN) atomicAdd(&counts[r * NN + d], 1);
    }
}

__global__ __launch_bounds__(256) void k_s1(const int* __restrict__ counts, int* __restrict__ bsum) {
    int r = blockIdx.y, b = blockIdx.x;
    int i = b * 256 + threadIdx.x;
    int v = (i < NN) ? counts[r * NN + i] : 0;
    #pragma unroll
    for (int m = 1; m < 64; m <<= 1) v += __shfl_xor(v, m);
    __shared__ int ws[4];
    int wid = threadIdx.x >> 6, lane = threadIdx.x & 63;
    if (lane == 0) ws[wid] = v;
    __syncthreads();
    if (threadIdx.x == 0) bsum[r * SNB + b] = ws[0] + ws[1] + ws[2] + ws[3];
}

__global__ __launch_bounds__(256) void k_s2(const int* __restrict__ bsum, int* __restrict__ boff) {
    int r = threadIdx.x >> 6;
    int lane = threadIdx.x & 63;
    int carry = 0;
    for (int c0 = 0; c0 < SNB; c0 += 64) {
        int b = c0 + lane;
        int v = (b < SNB) ? bsum[r * SNB + b] : 0;
        int inc = v;
        #pragma unroll
        for (int d = 1; d < 64; d <<= 1) {
            int t = __shfl_up(inc, d);
            if (lane >= d) inc += t;
        }
        if (b < SNB) boff[r * SNB + b] = carry + inc - v;
        carry += __shfl(inc, 63);
    }
}

// writes row_ptr AND initializes nxt (copynext folded in)
__global__ __launch_bounds__(256) void k_s3(const int* __restrict__ counts, const int* __restrict__ boff,
                                            int* __restrict__ row_ptr, int* __restrict__ nxt) {
    int r = blockIdx.y, b = blockIdx.x;
    int i = b * 256 + threadIdx.x;
    int v = (i < NN) ? counts[r * NN + i] : 0;
    int lane = threadIdx.x & 63, wid = threadIdx.x >> 6;
    int inc = v;
    #pragma unroll
    for (int d = 1; d < 64; d <<= 1) {
        int t = __shfl_up(inc, d);
        if (lane >= d) inc += t;
    }
    __shared__ int ws[4];
    if (lane == 63) ws[wid] = inc;
    __syncthreads();
    int woff = 0;
    #pragma unroll
    for (int w = 0; w < 4; ++w) woff += (w < wid) ? ws[w] : 0;
    if (i < NN) {
        int ex = boff[r * SNB + b] + woff + inc - v;
        row_ptr[r * (NN + 1) + i] = ex;
        nxt[r * NN + i] = ex;
    }
    if (b == 0 && threadIdx.x == 0) row_ptr[r * (NN + 1) + NN] = NEDGE;
}

__global__ __launch_bounds__(256) void k_fill(const int* __restrict__ src, const int* __restrict__ dst,
                                              int* __restrict__ nxt, int* __restrict__ csr) {
    int r = blockIdx.y;
    int i = blockIdx.x * 256 + threadIdx.x;
    if (i < NEDGE) {
        int d = dst[r * NEDGE + i];
        if ((unsigned)d >= NN) return;
        int pos = atomicAdd(&nxt[r * NN + d], 1);
        if ((unsigned)pos < NEDGE) csr[r * NEDGE + pos] = src[r * NEDGE + i];
    }
}

// ---------------- prep: wfrag + wl + wr + combined bias + h->bf16 ----------------
// per layer: 256 wfrag blocks + 128 wl blocks + 128 wr blocks = 512
__global__ __launch_bounds__(256) void k_prep(const float* __restrict__ Wsrc,
                                              const float* __restrict__ Wdst,
                                              const float* __restrict__ al,
                                              const float* __restrict__ ar,
                                              const float* __restrict__ ntb,
                                              const float* __restrict__ gb,
                                              const float* __restrict__ x,
                                              unsigned short* __restrict__ wf,
                                              float* __restrict__ wl,
                                              float* __restrict__ wr,
                                              float* __restrict__ biasc,
                                              unsigned short* __restrict__ xb) {
    int b = blockIdx.x;
    const int PL = NLAYER * 512;
    if (b < PL) {
        int l = b / 512;
        int t = b % 512;
        if (t < 256) {
            int idx = t * 256 + threadIdx.x;  // 0..65535
            int jj = idx & 7, lane = (idx >> 3) & 63, s = (idx >> 9) & 3, tt = (idx >> 11) & 7, r = idx >> 14;
            int k = s * 32 + ((lane >> 4) << 3) + jj;
            int n = tt * 16 + (lane & 15);
            wf[l * 65536 + idx] = f2bf(Wsrc[((size_t)(l * NREL + r) * DIM + k) * DIM + n]);
        } else if (t < 384) {
            int gw = (t - 256) * 4 + (threadIdx.x >> 6);  // 0..511 = r*128+k
            int lane = threadIdx.x & 63;
            int r = gw >> 7, k = gw & 127;
            const float* wrow = Wsrc + (((size_t)(l * NREL + r) * DIM + k) * DIM);
            const float* arow = al + (l * NREL + r) * DIM;
            float s = wrow[lane * 2] * arow[lane * 2] + wrow[lane * 2 + 1] * arow[lane * 2 + 1];
            #pragma unroll
            for (int m = 1; m < 64; m <<= 1) s += __shfl_xor(s, m);
            if (lane == 0) wl[l * 512 + gw] = s;
        } else {
            int gw = (t - 384) * 4 + (threadIdx.x >> 6);
            int lane = threadIdx.x & 63;
            int r = gw >> 7, k = gw & 127;
            const float* wrow = Wdst + (((size_t)(l * NREL + r) * DIM + k) * DIM);
            const float* arow = ar + (l * NREL + r) * DIM;
            float s = wrow[lane * 2] * arow[lane * 2] + wrow[lane * 2 + 1] * arow[lane * 2 + 1];
            #pragma unroll
            for (int m = 1; m < 64; m <<= 1) s += __shfl_xor(s, m);
            if (lane == 0) wr[l * 512 + gw] = s;
        }
    } else if (b < PL + 2) {
        int t = (b - PL) * 256 + threadIdx.x;
        if (t < NLAYER * DIM) {
            int l = t >> 7, k = t & 127;
            float s = ntb[t];
            #pragma unroll
            for (int r = 0; r < NREL; ++r) s += gb[(l * NREL + r) * DIM + k];
            biasc[t] = s;
        }
    } else {
        int i = ((b - PL - 2) * 256 + threadIdx.x) * 4;
        f32x4 v = *(const f32x4*)(x + i);
        unsigned short o[4];
        #pragma unroll
        for (int j = 0; j < 4; ++j) o[j] = f2bf(v[j]);
        *(ushort2*)(xb + i) = make_ushort2(o[0], o[1]);
        *(ushort2*)(xb + i + 2) = make_ushort2(o[2], o[3]);
    }
}

// ---------------- el/er for layer 0 from f32 h ----------------
__global__ __launch_bounds__(256) void k_er0(const float* __restrict__ x,
                                             const float* __restrict__ wl,
                                             const float* __restrict__ wr,
                                             float* __restrict__ el,
                                             float* __restrict__ er) {
    int oct = threadIdx.x >> 3, ol = threadIdx.x & 7;
    int n = blockIdx.x * 32 + oct;
    if (n >= NN) return;
    int f0 = ol * 16;
    const float* xp = x + (size_t)n * DIM + f0;
    f32x4 xv[4];
    #pragma unroll
    for (int k = 0; k < 4; ++k) xv[k] = *(const f32x4*)(xp + 4 * k);
    #pragma unroll
    for (int r = 0; r < NREL; ++r) {
        float sl = 0.f, sr = 0.f;
        #pragma unroll
        for (int k = 0; k < 4; ++k) {
            f32x4 lv = *(const f32x4*)(wl + r * DIM + f0 + 4 * k);
            f32x4 rv = *(const f32x4*)(wr + r * DIM + f0 + 4 * k);
            sl += xv[k][0] * lv[0] + xv[k][1] * lv[1] + xv[k][2] * lv[2] + xv[k][3] * lv[3];
            sr += xv[k][0] * rv[0] + xv[k][1] * rv[1] + xv[k][2] * rv[2] + xv[k][3] * rv[3];
        }
        sl += __shfl_xor(sl, 1); sl += __shfl_xor(sl, 2); sl += __shfl_xor(sl, 4);
        sr += __shfl_xor(sr, 1); sr += __shfl_xor(sr, 2); sr += __shfl_xor(sr, 4);
        if (ol == 0) { el[r * NN + n] = sl; er[r * NN + n] = sr; }
    }
}

// ---------------- fused layer: aggregate x -> LDS A-frags -> MFMA -> LN -> el'/er' ----------------
// 256 threads, 8 nodes/block (grid 6250). Phase 1: 8 lanes per (node,rel) pair =
// 2 edge-parity groups x 4 feature-lanes; chain = ceil(deg/2); partials merged via
// shfl_xor(.,4). A-frag rows 8..15 zero-padded (g==1 lanes). Phase 2: 4 waves x 2
// col-tiles (rows 8..15 of C discarded). Phase 3: 32 lanes per node, 8 nodes.
__global__ __launch_bounds__(256, 8) void k_fused(const unsigned short* __restrict__ xb,
                                               const float* __restrict__ el,
                                               const float* __restrict__ er,
                                               const int* __restrict__ row_ptr,
                                               const int* __restrict__ csr,
                                               const unsigned short* __restrict__ wf,
                                               const float* __restrict__ biasc,
                                               const float* __restrict__ lng,
                                               const float* __restrict__ lnb,
                                               const float* __restrict__ wl,
                                               const float* __restrict__ wr,
                                               float* __restrict__ dout,
                                               unsigned short* __restrict__ xb2,
                                               float* __restrict__ el2,
                                               float* __restrict__ er2,
                                               int l, int last) {
    __shared__ s16x8 lds_a[16 * 64];   // 16KB A-frags; reused as float C[16][128]
    int tid = threadIdx.x;

    // ---- phase 1: attention-weighted aggregation of x (bf16) ----
    {
        int pair = tid >> 3;        // 0..31
        int ol   = tid & 7;
        int g    = ol >> 2;         // edge-parity group (0/1)
        int fl   = ol & 3;          // feature lane in group
        int nd   = pair >> 2;       // 0..7
        int r    = pair & 3;
        int n    = blockIdx.x * NODES_PER_BLK + nd;
        int f0   = fl * 32;

        int start = row_ptr[r * (NN + 1) + n];
        int end   = row_ptr[r * (NN + 1) + n + 1];
        if (start < 0) start = 0;
        if (end > NEDGE) end = NEDGE;
        int deg = end - start;

        float ern = er[r * NN + n];
        const int* cp = csr + r * NEDGE;
        const float* elp = el + r * NN;

        f32x4 av[8] = {{0,0,0,0},{0,0,0,0},{0,0,0,0},{0,0,0,0},
                       {0,0,0,0},{0,0,0,0},{0,0,0,0},{0,0,0,0}};
        float denom = 0.f;
        int e = start + g;
        if (e < end) {
            int s0 = cp[e]; if ((unsigned)s0 >= NN) s0 = 0;
            float e0v = elp[s0];
            const uint4* hp = (const uint4*)(xb + (size_t)s0 * DIM + f0);
            uint4 xa = hp[0], xbv = hp[1], xc = hp[2], xd = hp[3];
            for (; e < end; e += 2) {
                int i1 = e + 2; i1 = (i1 < end) ? i1 : start;
                int s1 = cp[i1]; if ((unsigned)s1 >= NN) s1 = 0;
                float e1v = elp[s1];
                const uint4* hp1 = (const uint4*)(xb + (size_t)s1 * DIM + f0);
                uint4 ya = hp1[0], yb = hp1[1], yc = hp1[2], yd = hp1[3];

                float ev = e0v + ern;
                ev = ev >= 0.f ? ev : 0.2f * ev;
                ev = fminf(fmaxf(ev, -60.f), 60.f);
                float p = __expf(ev);
                denom += p;
                av[0][0] += p * lo_bf(xa.x); av[0][1] += p * hi_bf(xa.x);
                av[0][2] += p * lo_bf(xa.y); av[0][3] += p * hi_bf(xa.y);
                av[1][0] += p * lo_bf(xa.z); av[1][1] += p * hi_bf(xa.z);
                av[1][2] += p * lo_bf(xa.w); av[1][3] += p * hi_bf(xa.w);
                av[2][0] += p * lo_bf(xbv.x); av[2][1] += p * hi_bf(xbv.x);
                av[2][2] += p * lo_bf(xbv.y); av[2][3] += p * hi_bf(xbv.y);
                av[3][0] += p * lo_bf(xbv.z); av[3][1] += p * hi_bf(xbv.z);
                av[3][2] += p * lo_bf(xbv.w); av[3][3] += p * hi_bf(xbv.w);
                av[4][0] += p * lo_bf(xc.x); av[4][1] += p * hi_bf(xc.x);
                av[4][2] += p * lo_bf(xc.y); av[4][3] += p * hi_bf(xc.y);
                av[5][0] += p * lo_bf(xc.z); av[5][1] += p * hi_bf(xc.z);
                av[5][2] += p * lo_bf(xc.w); av[5][3] += p * hi_bf(xc.w);
                av[6][0] += p * lo_bf(xd.x); av[6][1] += p * hi_bf(xd.x);
                av[6][2] += p * lo_bf(xd.y); av[6][3] += p * hi_bf(xd.y);
                av[7][0] += p * lo_bf(xd.z); av[7][1] += p * hi_bf(xd.z);
                av[7][2] += p * lo_bf(xd.w); av[7][3] += p * hi_bf(xd.w);
                e0v = e1v; xa = ya; xbv = yb; xc = yc; xd = yd;
            }
        }
        // merge the two edge-parity groups (lanes ol and ol^4)
        denom += __shfl_xor(denom, 4);
        #pragma unroll
        for (int q = 0; q < 8; ++q) {
            #pragma unroll
            for (int j = 0; j < 4; ++j) av[q][j] += __shfl_xor(av[q][j], 4);
        }
        float inv = (deg > 0) ? (1.0f / denom) : 0.f;
        // pack to bf16 A-frags: lane covers k = r*128 + fl*32 + [0,32)
        // g==0 lanes write rows 0..7 (real); g==1 lanes zero rows 8..15.
        if (g == 0) {
            #pragma unroll
            for (int q = 0; q < 4; ++q) {
                s16x8 o;
                #pragma unroll
                for (int j = 0; j < 4; ++j) {
                    o[j]     = (short)f2bf(av[2 * q][j] * inv);
                    o[j + 4] = (short)f2bf(av[2 * q + 1][j] * inv);
                }
                lds_a[(r * 4 + fl) * 64 + q * 16 + nd] = o;
            }
        } else {
            s16x8 z = {0, 0, 0, 0, 0, 0, 0, 0};
            #pragma unroll
            for (int q = 0; q < 4; ++q)
                lds_a[(r * 4 + fl) * 64 + q * 16 + nd + 8] = z;
        }
    }
    __syncthreads();

    // ---- phase 2: C[16x128] = A[16x512] @ W[512x128]; 4 waves x 2 col-tiles ----
    int wv = tid >> 6, lane = tid & 63;
    int quad = lane >> 4, n16 = lane & 15;
    f32x4 acc0 = {0.f, 0.f, 0.f, 0.f}, acc1 = {0.f, 0.f, 0.f, 0.f};
    {
        const s16x8* wfp = (const s16x8*)wf + (size_t)l * NREL * 2048;
        int t0c = wv * 2, t1c = wv * 2 + 1;
        #pragma unroll
        for (int sp = 0; sp < 16; ++sp) {
            s16x8 a = lds_a[sp * 64 + lane];
            const s16x8* wb = wfp + (size_t)(sp >> 2) * 2048;
            int sl = sp & 3;
            s16x8 b0 = wb[(t0c * 4 + sl) * 64 + lane];
            s16x8 b1 = wb[(t1c * 4 + sl) * 64 + lane];
            acc0 = __builtin_amdgcn_mfma_f32_16x16x32_bf16(a, b0, acc0, 0, 0, 0);
            acc1 = __builtin_amdgcn_mfma_f32_16x16x32_bf16(a, b1, acc1, 0, 0, 0);
        }
    }
    __syncthreads();
    float* Cl = (float*)lds_a;
    {
        int t0c = wv * 2, t1c = wv * 2 + 1;
        #pragma unroll
        for (int reg = 0; reg < 4; ++reg) {
            int row = quad * 4 + reg;
            if (row < NODES_PER_BLK) {
                Cl[row * DIM + t0c * 16 + n16] = acc0[reg];
                Cl[row * DIM + t1c * 16 + n16] = acc1[reg];
            }
        }
    }
    __syncthreads();

    // ---- phase 3: bias + ReLU + LayerNorm + outputs + next-layer el'/er' ----
    {
        int nd2 = tid >> 5;         // 0..7
        int sub = tid & 31;
        int f   = sub * 4;
        int n2  = blockIdx.x * NODES_PER_BLK + nd2;

        float t[4];
        #pragma unroll
        for (int j = 0; j < 4; ++j) t[j] = Cl[nd2 * DIM + f + j] + biasc[l * DIM + f + j];
        if (!last) {
            #pragma unroll
            for (int j = 0; j < 4; ++j) t[j] = fmaxf(t[j], 0.f);
        }
        float s1 = 0.f;
        #pragma unroll
        for (int j = 0; j < 4; ++j) s1 += t[j];
        s1 += __shfl_xor(s1, 1); s1 += __shfl_xor(s1, 2);
        s1 += __shfl_xor(s1, 4); s1 += __shfl_xor(s1, 8);
        s1 += __shfl_xor(s1, 16);
        float mean = s1 * (1.0f / 128.0f);
        float s2 = 0.f;
        #pragma unroll
        for (int j = 0; j < 4; ++j) { t[j] -= mean; s2 += t[j] * t[j]; }
        s2 += __shfl_xor(s2, 1); s2 += __shfl_xor(s2, 2);
        s2 += __shfl_xor(s2, 4); s2 += __shfl_xor(s2, 8);
        s2 += __shfl_xor(s2, 16);
        float rs = rsqrtf(s2 * (1.0f / 128.0f) + 1e-5f);

        float y[4];
        #pragma unroll
        for (int j = 0; j < 4; ++j)
            y[j] = t[j] * rs * lng[l * DIM + f + j] + lnb[l * DIM + f + j];

        if (last) {
            float* op = dout + (size_t)n2 * DIM + f;
            f32x4 v0;
            v0[0] = y[0]; v0[1] = y[1]; v0[2] = y[2]; v0[3] = y[3];
            *(f32x4*)op = v0;
        } else {
            unsigned pk0 = (unsigned)f2bf(y[0]) | ((unsigned)f2bf(y[1]) << 16);
            unsigned pk1 = (unsigned)f2bf(y[2]) | ((unsigned)f2bf(y[3]) << 16);
            uint2 v; v.x = pk0; v.y = pk1;
            *(uint2*)(xb2 + (size_t)n2 * DIM + f) = v;

            const float* wlp = wl + (l + 1) * 512;
            const float* wrp = wr + (l + 1) * 512;
            #pragma unroll
            for (int rp = 0; rp < NREL; ++rp) {
                float sl_ = 0.f, sr_ = 0.f;
                #pragma unroll
                for (int j = 0; j < 4; ++j) {
                    sl_ += y[j] * wlp[rp * DIM + f + j];
                    sr_ += y[j] * wrp[rp * DIM + f + j];
                }
                sl_ += __shfl_xor(sl_, 1); sl_ += __shfl_xor(sl_, 2);
                sl_ += __shfl_xor(sl_, 4); sl_ += __shfl_xor(sl_, 8);
                sl_ += __shfl_xor(sl_, 16);
                sr_ += __shfl_xor(sr_, 1); sr_ += __shfl_xor(sr_, 2);
                sr_ += __shfl_xor(sr_, 4); sr_ += __shfl_xor(sr_, 8);
                sr_ += __shfl_xor(sr_, 16);
                if (sub == 0) {
                    el2[rp * NN + n2] = sl_;
                    er2[rp * NN + n2] = sr_;
                }
            }
        }
    }
}

extern "C" void kernel_launch(void* const* d_in, const int* in_sizes, int n_in,
                              void* d_out, int out_size, void* d_ws, size_t ws_size,
                              hipStream_t stream) {
    const float* h        = (const float*)d_in[0];
    const int*   edge_src = (const int*)d_in[1];
    const int*   edge_dst = (const int*)d_in[2];
    const float* W_src    = (const float*)d_in[3];
    const float* W_dst    = (const float*)d_in[4];
    const float* attn_l   = (const float*)d_in[5];
    const float* attn_r   = (const float*)d_in[6];
    const float* gat_bias = (const float*)d_in[7];
    const float* ntype_b  = (const float*)d_in[8];
    const float* ln_g     = (const float*)d_in[9];
    const float* ln_b     = (const float*)d_in[10];

    if (n_in < 11) return;
    if (in_sizes[0] != NN * DIM) return;
    if (in_sizes[1] != NREL * NEDGE || in_sizes[2] != NREL * NEDGE) return;
    if (in_sizes[3] != NLAYER * NREL * DIM * DIM || in_sizes[4] != NLAYER * NREL * DIM * DIM) return;
    if (in_sizes[5] != NLAYER * NREL * DIM || in_sizes[6] != NLAYER * NREL * DIM) return;
    if (in_sizes[7] != NLAYER * NREL * DIM || in_sizes[8] != NLAYER * DIM) return;
    if (out_size != NN * DIM) return;

    auto align256 = [](size_t x) { return (x + 255) & ~(size_t)255; };
    size_t szElEr = align256((size_t)NREL * NN * 4);            // x4 buffers
    size_t szXbf  = align256((size_t)NN * DIM * 2);             // x2 buffers
    size_t szWlr  = align256((size_t)NLAYER * 512 * 4);         // x2
    size_t szBc   = align256((size_t)NLAYER * DIM * 4);
    size_t szWf   = align256((size_t)NLAYER * NREL * DIM * DIM * 2);
    size_t szRp   = align256((size_t)NREL * (NN + 1) * 4);
    size_t szNxt  = align256((size_t)NREL * NN * 4);
    size_t szCsr  = align256((size_t)NREL * NEDGE * 4);
    size_t szScn  = align256((size_t)NREL * SNB * 4) * 2;
    size_t need = 4 * szElEr + 2 * szXbf + 2 * szWlr + szBc + szWf + szRp + szNxt + szCsr + szScn;

    if (ws_size < need) {
        k_constf<<<(NN * DIM + 255) / 256, 256, 0, stream>>>((float*)d_out, NN * DIM, 100.0f);
        return;
    }

    char* base = (char*)d_ws;
    size_t off = 0;
    auto alloc = [&](size_t bytes) -> char* { char* p = base + off; off += align256(bytes); return p; };

    float* el   = (float*)alloc((size_t)NREL * NN * 4);
    float* er   = (float*)alloc((size_t)NREL * NN * 4);
    float* el2  = (float*)alloc((size_t)NREL * NN * 4);
    float* er2  = (float*)alloc((size_t)NREL * NN * 4);
    unsigned short* xbf  = (unsigned short*)alloc((size_t)NN * DIM * 2);
    unsigned short* xbf2 = (unsigned short*)alloc((size_t)NN * DIM * 2);
    float* wl    = (float*)alloc((size_t)NLAYER * 512 * 4);
    float* wr    = (float*)alloc((size_t)NLAYER * 512 * 4);
    float* biasc = (float*)alloc((size_t)NLAYER * DIM * 4);
    unsigned short* wfrag = (unsigned short*)alloc((size_t)NLAYER * NREL * DIM * DIM * 2);
    int* rowp = (int*)alloc((size_t)NREL * (NN + 1) * 4);
    int* nxt  = (int*)alloc((size_t)NREL * NN * 4);
    int* csr  = (int*)alloc((size_t)NREL * NEDGE * 4);
    int* bsum = (int*)alloc((size_t)NREL * SNB * 4);
    int* boff = (int*)alloc((size_t)NREL * SNB * 4);

    // ---- CSR build + prep + layer-0 el/er ----
    (void)hipMemsetAsync(nxt, 0, (size_t)NREL * NN * 4, stream);
    k_count<<<dim3((NEDGE + 255) / 256, NREL), 256, 0, stream>>>(edge_dst, nxt);
    k_s1<<<dim3(SNB, NREL), 256, 0, stream>>>(nxt, bsum);
    k_s2<<<1, 256, 0, stream>>>(bsum, boff);
    k_s3<<<dim3(SNB, NREL), 256, 0, stream>>>(nxt, boff, rowp, nxt);
    k_fill<<<dim3((NEDGE + 255) / 256, NREL), 256, 0, stream>>>(edge_src, edge_dst, nxt, csr);
    k_prep<<<NLAYER * 512 + 2 + NN * DIM / 1024, 256, 0, stream>>>(
        W_src, W_dst, attn_l, attn_r, ntype_b, gat_bias, h, wfrag, wl, wr, biasc, xbf);
    k_er0<<<(NN + 31) / 32, 256, 0, stream>>>(h, wl, wr, el, er);

    // ---- layers (ping-pong xbf / el / er) ----
    float* dout = (float*)d_out;
    // l = 0: in (xbf, el, er) -> out (xbf2, el2, er2)
    k_fused<<<NN / NODES_PER_BLK, 256, 0, stream>>>(xbf, el, er, rowp, csr, wfrag, biasc, ln_g, ln_b,
                                         wl, wr, dout, xbf2, el2, er2, 0, 0);
    // l = 1: in (xbf2, el2, er2) -> out (xbf, el, er)
    k_fused<<<NN / NODES_PER_BLK, 256, 0, stream>>>(xbf2, el2, er2, rowp, csr, wfrag, biasc, ln_g, ln_b,
                                         wl, wr, dout, xbf, el, er, 1, 0);
    // l = 2 (last): in (xbf, el, er) -> d_out
    k_fused<<<NN / NODES_PER_BLK, 256, 0, stream>>>(xbf, el, er, rowp, csr, wfrag, biasc, ln_g, ln_b,
                                         wl, wr, dout, xbf2, el2, er2, 2, 1);
}

// Round 4
// 411.517 us; speedup vs baseline: 1.2794x; 1.2794x over previous
//
#include <hip/hip_runtime.h>

#define NN 50000
#define DIM 128
#define NREL 4
#define NEDGE 200000
#define NLAYER 3
#define SNB 196  // ceil(NN/256)
#define NODES_PER_BLK 8

typedef short s16x8 __attribute__((ext_vector_type(8)));
typedef float f32x4 __attribute__((ext_vector_type(4)));

__device__ __forceinline__ unsigned short f2bf(float f) {
    union { float f; unsigned u; } c; c.f = f;
    unsigned u = c.u + 0x7fffu + ((c.u >> 16) & 1u);
    return (unsigned short)(u >> 16);
}
__device__ __forceinline__ float lo_bf(unsigned u) {
    union { float f; unsigned u; } c; c.u = u << 16; return c.f;
}
__device__ __forceinline__ float hi_bf(unsigned u) {
    union { float f; unsigned u; } c; c.u = u & 0xffff0000u; return c.f;
}

// ---------------- diagnostics ----------------
__global__ __launch_bounds__(256) void k_constf(float* __restrict__ out, int n, float v) {
    int i = blockIdx.x * 256 + threadIdx.x;
    if (i < n) out[i] = v;
}

// ---------------- CSR build ----------------
__global__ __launch_bounds__(256) void k_count(const int* __restrict__ dst, int* __restrict__ counts) {
    int r = blockIdx.y;
    int i = blockIdx.x * 256 + threadIdx.x;
    if (i < NEDGE) {
        int d = dst[r * NEDGE + i];
        if ((unsigned)d < NN) atomicAdd(&counts[r * NN + d], 1);
    }
}

__global__ __launch_bounds__(256) void k_s1(const int* __restrict__ counts, int* __restrict__ bsum) {
    int r = blockIdx.y, b = blockIdx.x;
    int i = b * 256 + threadIdx.x;
    int v = (i < NN) ? counts[r * NN + i] : 0;
    #pragma unroll
    for (int m = 1; m < 64; m <<= 1) v += __shfl_xor(v, m);
    __shared__ int ws[4];
    int wid = threadIdx.x >> 6, lane = threadIdx.x & 63;
    if (lane == 0) ws[wid] = v;
    __syncthreads();
    if (threadIdx.x == 0) bsum[r * SNB + b] = ws[0] + ws[1] + ws[2] + ws[3];
}

__global__ __launch_bounds__(256) void k_s2(const int* __restrict__ bsum, int* __restrict__ boff) {
    int r = threadIdx.x >> 6;
    int lane = threadIdx.x & 63;
    int carry = 0;
    for (int c0 = 0; c0 < SNB; c0 += 64) {
        int b = c0 + lane;
        int v = (b < SNB) ? bsum[r * SNB + b] : 0;
        int inc = v;
        #pragma unroll
        for (int d = 1; d < 64; d <<= 1) {
            int t = __shfl_up(inc, d);
            if (lane >= d) inc += t;
        }
        if (b < SNB) boff[r * SNB + b] = carry + inc - v;
        carry += __shfl(inc, 63);
    }
}

// writes row_ptr AND initializes nxt (copynext folded in)
__global__ __launch_bounds__(256) void k_s3(const int* __restrict__ counts, const int* __restrict__ boff,
                                            int* __restrict__ row_ptr, int* __restrict__ nxt) {
    int r = blockIdx.y, b = blockIdx.x;
    int i = b * 256 + threadIdx.x;
    int v = (i < NN) ? counts[r * NN + i] : 0;
    int lane = threadIdx.x & 63, wid = threadIdx.x >> 6;
    int inc = v;
    #pragma unroll
    for (int d = 1; d < 64; d <<= 1) {
        int t = __shfl_up(inc, d);
        if (lane >= d) inc += t;
    }
    __shared__ int ws[4];
    if (lane == 63) ws[wid] = inc;
    __syncthreads();
    int woff = 0;
    #pragma unroll
    for (int w = 0; w < 4; ++w) woff += (w < wid) ? ws[w] : 0;
    if (i < NN) {
        int ex = boff[r * SNB + b] + woff + inc - v;
        row_ptr[r * (NN + 1) + i] = ex;
        nxt[r * NN + i] = ex;
    }
    if (b == 0 && threadIdx.x == 0) row_ptr[r * (NN + 1) + NN] = NEDGE;
}

__global__ __launch_bounds__(256) void k_fill(const int* __restrict__ src, const int* __restrict__ dst,
                                              int* __restrict__ nxt, int* __restrict__ csr) {
    int r = blockIdx.y;
    int i = blockIdx.x * 256 + threadIdx.x;
    if (i < NEDGE) {
        int d = dst[r * NEDGE + i];
        if ((unsigned)d >= NN) return;
        int pos = atomicAdd(&nxt[r * NN + d], 1);
        if ((unsigned)pos < NEDGE) csr[r * NEDGE + pos] = src[r * NEDGE + i];
    }
}

// ---------------- prep: wfrag + wl + wr + combined bias + h->bf16 ----------------
// per layer: 256 wfrag blocks + 128 wl blocks + 128 wr blocks = 512
__global__ __launch_bounds__(256) void k_prep(const float* __restrict__ Wsrc,
                                              const float* __restrict__ Wdst,
                                              const float* __restrict__ al,
                                              const float* __restrict__ ar,
                                              const float* __restrict__ ntb,
                                              const float* __restrict__ gb,
                                              const float* __restrict__ x,
                                              unsigned short* __restrict__ wf,
                                              float* __restrict__ wl,
                                              float* __restrict__ wr,
                                              float* __restrict__ biasc,
                                              unsigned short* __restrict__ xb) {
    int b = blockIdx.x;
    const int PL = NLAYER * 512;
    if (b < PL) {
        int l = b / 512;
        int t = b % 512;
        if (t < 256) {
            int idx = t * 256 + threadIdx.x;  // 0..65535
            int jj = idx & 7, lane = (idx >> 3) & 63, s = (idx >> 9) & 3, tt = (idx >> 11) & 7, r = idx >> 14;
            int k = s * 32 + ((lane >> 4) << 3) + jj;
            int n = tt * 16 + (lane & 15);
            wf[l * 65536 + idx] = f2bf(Wsrc[((size_t)(l * NREL + r) * DIM + k) * DIM + n]);
        } else if (t < 384) {
            int gw = (t - 256) * 4 + (threadIdx.x >> 6);  // 0..511 = r*128+k
            int lane = threadIdx.x & 63;
            int r = gw >> 7, k = gw & 127;
            const float* wrow = Wsrc + (((size_t)(l * NREL + r) * DIM + k) * DIM);
            const float* arow = al + (l * NREL + r) * DIM;
            float s = wrow[lane * 2] * arow[lane * 2] + wrow[lane * 2 + 1] * arow[lane * 2 + 1];
            #pragma unroll
            for (int m = 1; m < 64; m <<= 1) s += __shfl_xor(s, m);
            if (lane == 0) wl[l * 512 + gw] = s;
        } else {
            int gw = (t - 384) * 4 + (threadIdx.x >> 6);
            int lane = threadIdx.x & 63;
            int r = gw >> 7, k = gw & 127;
            const float* wrow = Wdst + (((size_t)(l * NREL + r) * DIM + k) * DIM);
            const float* arow = ar + (l * NREL + r) * DIM;
            float s = wrow[lane * 2] * arow[lane * 2] + wrow[lane * 2 + 1] * arow[lane * 2 + 1];
            #pragma unroll
            for (int m = 1; m < 64; m <<= 1) s += __shfl_xor(s, m);
            if (lane == 0) wr[l * 512 + gw] = s;
        }
    } else if (b < PL + 2) {
        int t = (b - PL) * 256 + threadIdx.x;
        if (t < NLAYER * DIM) {
            int l = t >> 7, k = t & 127;
            float s = ntb[t];
            #pragma unroll
            for (int r = 0; r < NREL; ++r) s += gb[(l * NREL + r) * DIM + k];
            biasc[t] = s;
        }
    } else {
        int i = ((b - PL - 2) * 256 + threadIdx.x) * 4;
        f32x4 v = *(const f32x4*)(x + i);
        unsigned short o[4];
        #pragma unroll
        for (int j = 0; j < 4; ++j) o[j] = f2bf(v[j]);
        *(ushort2*)(xb + i) = make_ushort2(o[0], o[1]);
        *(ushort2*)(xb + i + 2) = make_ushort2(o[2], o[3]);
    }
}

// ---------------- el/er for layer 0 from f32 h ----------------
__global__ __launch_bounds__(256) void k_er0(const float* __restrict__ x,
                                             const float* __restrict__ wl,
                                             const float* __restrict__ wr,
                                             float* __restrict__ el,
                                             float* __restrict__ er) {
    int oct = threadIdx.x >> 3, ol = threadIdx.x & 7;
    int n = blockIdx.x * 32 + oct;
    if (n >= NN) return;
    int f0 = ol * 16;
    const float* xp = x + (size_t)n * DIM + f0;
    f32x4 xv[4];
    #pragma unroll
    for (int k = 0; k < 4; ++k) xv[k] = *(const f32x4*)(xp + 4 * k);
    #pragma unroll
    for (int r = 0; r < NREL; ++r) {
        float sl = 0.f, sr = 0.f;
        #pragma unroll
        for (int k = 0; k < 4; ++k) {
            f32x4 lv = *(const f32x4*)(wl + r * DIM + f0 + 4 * k);
            f32x4 rv = *(const f32x4*)(wr + r * DIM + f0 + 4 * k);
            sl += xv[k][0] * lv[0] + xv[k][1] * lv[1] + xv[k][2] * lv[2] + xv[k][3] * lv[3];
            sr += xv[k][0] * rv[0] + xv[k][1] * rv[1] + xv[k][2] * rv[2] + xv[k][3] * rv[3];
        }
        sl += __shfl_xor(sl, 1); sl += __shfl_xor(sl, 2); sl += __shfl_xor(sl, 4);
        sr += __shfl_xor(sr, 1); sr += __shfl_xor(sr, 2); sr += __shfl_xor(sr, 4);
        if (ol == 0) { el[r * NN + n] = sl; er[r * NN + n] = sr; }
    }
}

// ---------------- fused layer: aggregate x -> LDS A-frags -> MFMA -> LN -> el'/er' ----------------
// 256 threads, 8 nodes/block (grid 6250). Phase 1: 8 lanes per (node,rel) pair =
// 2 edge-parity groups x 4 feature-lanes; chain = ceil(deg/2); partials merged via
// shfl_xor(.,4). A-frag rows 8..15 zero-padded (g==1 lanes). Phase 2: 4 waves x 2
// col-tiles (rows 8..15 of C discarded). Phase 3: 32 lanes per node, 8 nodes.
// NOTE: no min-waves bound — (256,8) forced 32 VGPR and spilled av[] to scratch
// (WRITE_SIZE 14->206MB). Natural alloc ~44-48 VGPR <= 64 keeps full wave slots.
__global__ __launch_bounds__(256) void k_fused(const unsigned short* __restrict__ xb,
                                               const float* __restrict__ el,
                                               const float* __restrict__ er,
                                               const int* __restrict__ row_ptr,
                                               const int* __restrict__ csr,
                                               const unsigned short* __restrict__ wf,
                                               const float* __restrict__ biasc,
                                               const float* __restrict__ lng,
                                               const float* __restrict__ lnb,
                                               const float* __restrict__ wl,
                                               const float* __restrict__ wr,
                                               float* __restrict__ dout,
                                               unsigned short* __restrict__ xb2,
                                               float* __restrict__ el2,
                                               float* __restrict__ er2,
                                               int l, int last) {
    __shared__ s16x8 lds_a[16 * 64];   // 16KB A-frags; reused as float C[16][128]
    int tid = threadIdx.x;

    // ---- phase 1: attention-weighted aggregation of x (bf16) ----
    {
        int pair = tid >> 3;        // 0..31
        int ol   = tid & 7;
        int g    = ol >> 2;         // edge-parity group (0/1)
        int fl   = ol & 3;          // feature lane in group
        int nd   = pair >> 2;       // 0..7
        int r    = pair & 3;
        int n    = blockIdx.x * NODES_PER_BLK + nd;
        int f0   = fl * 32;

        int start = row_ptr[r * (NN + 1) + n];
        int end   = row_ptr[r * (NN + 1) + n + 1];
        if (start < 0) start = 0;
        if (end > NEDGE) end = NEDGE;
        int deg = end - start;

        float ern = er[r * NN + n];
        const int* cp = csr + r * NEDGE;
        const float* elp = el + r * NN;

        f32x4 av[8] = {{0,0,0,0},{0,0,0,0},{0,0,0,0},{0,0,0,0},
                       {0,0,0,0},{0,0,0,0},{0,0,0,0},{0,0,0,0}};
        float denom = 0.f;
        int e = start + g;
        if (e < end) {
            int s0 = cp[e]; if ((unsigned)s0 >= NN) s0 = 0;
            float e0v = elp[s0];
            const uint4* hp = (const uint4*)(xb + (size_t)s0 * DIM + f0);
            uint4 xa = hp[0], xbv = hp[1], xc = hp[2], xd = hp[3];
            for (; e < end; e += 2) {
                int i1 = e + 2; i1 = (i1 < end) ? i1 : start;
                int s1 = cp[i1]; if ((unsigned)s1 >= NN) s1 = 0;
                float e1v = elp[s1];
                const uint4* hp1 = (const uint4*)(xb + (size_t)s1 * DIM + f0);
                uint4 ya = hp1[0], yb = hp1[1], yc = hp1[2], yd = hp1[3];

                float ev = e0v + ern;
                ev = ev >= 0.f ? ev : 0.2f * ev;
                ev = fminf(fmaxf(ev, -60.f), 60.f);
                float p = __expf(ev);
                denom += p;
                av[0][0] += p * lo_bf(xa.x); av[0][1] += p * hi_bf(xa.x);
                av[0][2] += p * lo_bf(xa.y); av[0][3] += p * hi_bf(xa.y);
                av[1][0] += p * lo_bf(xa.z); av[1][1] += p * hi_bf(xa.z);
                av[1][2] += p * lo_bf(xa.w); av[1][3] += p * hi_bf(xa.w);
                av[2][0] += p * lo_bf(xbv.x); av[2][1] += p * hi_bf(xbv.x);
                av[2][2] += p * lo_bf(xbv.y); av[2][3] += p * hi_bf(xbv.y);
                av[3][0] += p * lo_bf(xbv.z); av[3][1] += p * hi_bf(xbv.z);
                av[3][2] += p * lo_bf(xbv.w); av[3][3] += p * hi_bf(xbv.w);
                av[4][0] += p * lo_bf(xc.x); av[4][1] += p * hi_bf(xc.x);
                av[4][2] += p * lo_bf(xc.y); av[4][3] += p * hi_bf(xc.y);
                av[5][0] += p * lo_bf(xc.z); av[5][1] += p * hi_bf(xc.z);
                av[5][2] += p * lo_bf(xc.w); av[5][3] += p * hi_bf(xc.w);
                av[6][0] += p * lo_bf(xd.x); av[6][1] += p * hi_bf(xd.x);
                av[6][2] += p * lo_bf(xd.y); av[6][3] += p * hi_bf(xd.y);
                av[7][0] += p * lo_bf(xd.z); av[7][1] += p * hi_bf(xd.z);
                av[7][2] += p * lo_bf(xd.w); av[7][3] += p * hi_bf(xd.w);
                e0v = e1v; xa = ya; xbv = yb; xc = yc; xd = yd;
            }
        }
        // merge the two edge-parity groups (lanes ol and ol^4)
        denom += __shfl_xor(denom, 4);
        #pragma unroll
        for (int q = 0; q < 8; ++q) {
            #pragma unroll
            for (int j = 0; j < 4; ++j) av[q][j] += __shfl_xor(av[q][j], 4);
        }
        float inv = (deg > 0) ? (1.0f / denom) : 0.f;
        // pack to bf16 A-frags: lane covers k = r*128 + fl*32 + [0,32)
        // g==0 lanes write rows 0..7 (real); g==1 lanes zero rows 8..15.
        if (g == 0) {
            #pragma unroll
            for (int q = 0; q < 4; ++q) {
                s16x8 o;
                #pragma unroll
                for (int j = 0; j < 4; ++j) {
                    o[j]     = (short)f2bf(av[2 * q][j] * inv);
                    o[j + 4] = (short)f2bf(av[2 * q + 1][j] * inv);
                }
                lds_a[(r * 4 + fl) * 64 + q * 16 + nd] = o;
            }
        } else {
            s16x8 z = {0, 0, 0, 0, 0, 0, 0, 0};
            #pragma unroll
            for (int q = 0; q < 4; ++q)
                lds_a[(r * 4 + fl) * 64 + q * 16 + nd + 8] = z;
        }
    }
    __syncthreads();

    // ---- phase 2: C[16x128] = A[16x512] @ W[512x128]; 4 waves x 2 col-tiles ----
    int wv = tid >> 6, lane = tid & 63;
    int quad = lane >> 4, n16 = lane & 15;
    f32x4 acc0 = {0.f, 0.f, 0.f, 0.f}, acc1 = {0.f, 0.f, 0.f, 0.f};
    {
        const s16x8* wfp = (const s16x8*)wf + (size_t)l * NREL * 2048;
        int t0c = wv * 2, t1c = wv * 2 + 1;
        #pragma unroll
        for (int sp = 0; sp < 16; ++sp) {
            s16x8 a = lds_a[sp * 64 + lane];
            const s16x8* wb = wfp + (size_t)(sp >> 2) * 2048;
            int sl = sp & 3;
            s16x8 b0 = wb[(t0c * 4 + sl) * 64 + lane];
            s16x8 b1 = wb[(t1c * 4 + sl) * 64 + lane];
            acc0 = __builtin_amdgcn_mfma_f32_16x16x32_bf16(a, b0, acc0, 0, 0, 0);
            acc1 = __builtin_amdgcn_mfma_f32_16x16x32_bf16(a, b1, acc1, 0, 0, 0);
        }
    }
    __syncthreads();
    float* Cl = (float*)lds_a;
    {
        int t0c = wv * 2, t1c = wv * 2 + 1;
        #pragma unroll
        for (int reg = 0; reg < 4; ++reg) {
            int row = quad * 4 + reg;
            if (row < NODES_PER_BLK) {
                Cl[row * DIM + t0c * 16 + n16] = acc0[reg];
                Cl[row * DIM + t1c * 16 + n16] = acc1[reg];
            }
        }
    }
    __syncthreads();

    // ---- phase 3: bias + ReLU + LayerNorm + outputs + next-layer el'/er' ----
    {
        int nd2 = tid >> 5;         // 0..7
        int sub = tid & 31;
        int f   = sub * 4;
        int n2  = blockIdx.x * NODES_PER_BLK + nd2;

        float t[4];
        #pragma unroll
        for (int j = 0; j < 4; ++j) t[j] = Cl[nd2 * DIM + f + j] + biasc[l * DIM + f + j];
        if (!last) {
            #pragma unroll
            for (int j = 0; j < 4; ++j) t[j] = fmaxf(t[j], 0.f);
        }
        float s1 = 0.f;
        #pragma unroll
        for (int j = 0; j < 4; ++j) s1 += t[j];
        s1 += __shfl_xor(s1, 1); s1 += __shfl_xor(s1, 2);
        s1 += __shfl_xor(s1, 4); s1 += __shfl_xor(s1, 8);
        s1 += __shfl_xor(s1, 16);
        float mean = s1 * (1.0f / 128.0f);
        float s2 = 0.f;
        #pragma unroll
        for (int j = 0; j < 4; ++j) { t[j] -= mean; s2 += t[j] * t[j]; }
        s2 += __shfl_xor(s2, 1); s2 += __shfl_xor(s2, 2);
        s2 += __shfl_xor(s2, 4); s2 += __shfl_xor(s2, 8);
        s2 += __shfl_xor(s2, 16);
        float rs = rsqrtf(s2 * (1.0f / 128.0f) + 1e-5f);

        float y[4];
        #pragma unroll
        for (int j = 0; j < 4; ++j)
            y[j] = t[j] * rs * lng[l * DIM + f + j] + lnb[l * DIM + f + j];

        if (last) {
            float* op = dout + (size_t)n2 * DIM + f;
            f32x4 v0;
            v0[0] = y[0]; v0[1] = y[1]; v0[2] = y[2]; v0[3] = y[3];
            *(f32x4*)op = v0;
        } else {
            unsigned pk0 = (unsigned)f2bf(y[0]) | ((unsigned)f2bf(y[1]) << 16);
            unsigned pk1 = (unsigned)f2bf(y[2]) | ((unsigned)f2bf(y[3]) << 16);
            uint2 v; v.x = pk0; v.y = pk1;
            *(uint2*)(xb2 + (size_t)n2 * DIM + f) = v;

            const float* wlp = wl + (l + 1) * 512;
            const float* wrp = wr + (l + 1) * 512;
            #pragma unroll
            for (int rp = 0; rp < NREL; ++rp) {
                float sl_ = 0.f, sr_ = 0.f;
                #pragma unroll
                for (int j = 0; j < 4; ++j) {
                    sl_ += y[j] * wlp[rp * DIM + f + j];
                    sr_ += y[j] * wrp[rp * DIM + f + j];
                }
                sl_ += __shfl_xor(sl_, 1); sl_ += __shfl_xor(sl_, 2);
                sl_ += __shfl_xor(sl_, 4); sl_ += __shfl_xor(sl_, 8);
                sl_ += __shfl_xor(sl_, 16);
                sr_ += __shfl_xor(sr_, 1); sr_ += __shfl_xor(sr_, 2);
                sr_ += __shfl_xor(sr_, 4); sr_ += __shfl_xor(sr_, 8);
                sr_ += __shfl_xor(sr_, 16);
                if (sub == 0) {
                    el2[rp * NN + n2] = sl_;
                    er2[rp * NN + n2] = sr_;
                }
            }
        }
    }
}

extern "C" void kernel_launch(void* const* d_in, const int* in_sizes, int n_in,
                              void* d_out, int out_size, void* d_ws, size_t ws_size,
                              hipStream_t stream) {
    const float* h        = (const float*)d_in[0];
    const int*   edge_src = (const int*)d_in[1];
    const int*   edge_dst = (const int*)d_in[2];
    const float* W_src    = (const float*)d_in[3];
    const float* W_dst    = (const float*)d_in[4];
    const float* attn_l   = (const float*)d_in[5];
    const float* attn_r   = (const float*)d_in[6];
    const float* gat_bias = (const float*)d_in[7];
    const float* ntype_b  = (const float*)d_in[8];
    const float* ln_g     = (const float*)d_in[9];
    const float* ln_b     = (const float*)d_in[10];

    if (n_in < 11) return;
    if (in_sizes[0] != NN * DIM) return;
    if (in_sizes[1] != NREL * NEDGE || in_sizes[2] != NREL * NEDGE) return;
    if (in_sizes[3] != NLAYER * NREL * DIM * DIM || in_sizes[4] != NLAYER * NREL * DIM * DIM) return;
    if (in_sizes[5] != NLAYER * NREL * DIM || in_sizes[6] != NLAYER * NREL * DIM) return;
    if (in_sizes[7] != NLAYER * NREL * DIM || in_sizes[8] != NLAYER * DIM) return;
    if (out_size != NN * DIM) return;

    auto align256 = [](size_t x) { return (x + 255) & ~(size_t)255; };
    size_t szElEr = align256((size_t)NREL * NN * 4);            // x4 buffers
    size_t szXbf  = align256((size_t)NN * DIM * 2);             // x2 buffers
    size_t szWlr  = align256((size_t)NLAYER * 512 * 4);         // x2
    size_t szBc   = align256((size_t)NLAYER * DIM * 4);
    size_t szWf   = align256((size_t)NLAYER * NREL * DIM * DIM * 2);
    size_t szRp   = align256((size_t)NREL * (NN + 1) * 4);
    size_t szNxt  = align256((size_t)NREL * NN * 4);
    size_t szCsr  = align256((size_t)NREL * NEDGE * 4);
    size_t szScn  = align256((size_t)NREL * SNB * 4) * 2;
    size_t need = 4 * szElEr + 2 * szXbf + 2 * szWlr + szBc + szWf + szRp + szNxt + szCsr + szScn;

    if (ws_size < need) {
        k_constf<<<(NN * DIM + 255) / 256, 256, 0, stream>>>((float*)d_out, NN * DIM, 100.0f);
        return;
    }

    char* base = (char*)d_ws;
    size_t off = 0;
    auto alloc = [&](size_t bytes) -> char* { char* p = base + off; off += align256(bytes); return p; };

    float* el   = (float*)alloc((size_t)NREL * NN * 4);
    float* er   = (float*)alloc((size_t)NREL * NN * 4);
    float* el2  = (float*)alloc((size_t)NREL * NN * 4);
    float* er2  = (float*)alloc((size_t)NREL * NN * 4);
    unsigned short* xbf  = (unsigned short*)alloc((size_t)NN * DIM * 2);
    unsigned short* xbf2 = (unsigned short*)alloc((size_t)NN * DIM * 2);
    float* wl    = (float*)alloc((size_t)NLAYER * 512 * 4);
    float* wr    = (float*)alloc((size_t)NLAYER * 512 * 4);
    float* biasc = (float*)alloc((size_t)NLAYER * DIM * 4);
    unsigned short* wfrag = (unsigned short*)alloc((size_t)NLAYER * NREL * DIM * DIM * 2);
    int* rowp = (int*)alloc((size_t)NREL * (NN + 1) * 4);
    int* nxt  = (int*)alloc((size_t)NREL * NN * 4);
    int* csr  = (int*)alloc((size_t)NREL * NEDGE * 4);
    int* bsum = (int*)alloc((size_t)NREL * SNB * 4);
    int* boff = (int*)alloc((size_t)NREL * SNB * 4);

    // ---- CSR build + prep + layer-0 el/er ----
    (void)hipMemsetAsync(nxt, 0, (size_t)NREL * NN * 4, stream);
    k_count<<<dim3((NEDGE + 255) / 256, NREL), 256, 0, stream>>>(edge_dst, nxt);
    k_s1<<<dim3(SNB, NREL), 256, 0, stream>>>(nxt, bsum);
    k_s2<<<1, 256, 0, stream>>>(bsum, boff);
    k_s3<<<dim3(SNB, NREL), 256, 0, stream>>>(nxt, boff, rowp, nxt);
    k_fill<<<dim3((NEDGE + 255) / 256, NREL), 256, 0, stream>>>(edge_src, edge_dst, nxt, csr);
    k_prep<<<NLAYER * 512 + 2 + NN * DIM / 1024, 256, 0, stream>>>(
        W_src, W_dst, attn_l, attn_r, ntype_b, gat_bias, h, wfrag, wl, wr, biasc, xbf);
    k_er0<<<(NN + 31) / 32, 256, 0, stream>>>(h, wl, wr, el, er);

    // ---- layers (ping-pong xbf / el / er) ----
    float* dout = (float*)d_out;
    // l = 0: in (xbf, el, er) -> out (xbf2, el2, er2)
    k_fused<<<NN / NODES_PER_BLK, 256, 0, stream>>>(xbf, el, er, rowp, csr, wfrag, biasc, ln_g, ln_b,
                                         wl, wr, dout, xbf2, el2, er2, 0, 0);
    // l = 1: in (xbf2, el2, er2) -> out (xbf, el, er)
    k_fused<<<NN / NODES_PER_BLK, 256, 0, stream>>>(xbf2, el2, er2, rowp, csr, wfrag, biasc, ln_g, ln_b,
                                         wl, wr, dout, xbf, el, er, 1, 0);
    // l = 2 (last): in (xbf, el, er) -> d_out
    k_fused<<<NN / NODES_PER_BLK, 256, 0, stream>>>(xbf, el, er, rowp, csr, wfrag, biasc, ln_g, ln_b,
                                         wl, wr, dout, xbf2, el2, er2, 2, 1);
}

// Round 5
// 367.591 us; speedup vs baseline: 1.4323x; 1.1195x over previous
//
#include <hip/hip_runtime.h>

#define NN 50000
#define DIM 128
#define NREL 4
#define NEDGE 200000
#define NLAYER 3
#define SNB 196  // ceil(NN/256)
#define NODES_PER_BLK 32

typedef short s16x8 __attribute__((ext_vector_type(8)));
typedef float f32x4 __attribute__((ext_vector_type(4)));

__device__ __forceinline__ unsigned short f2bf(float f) {
    union { float f; unsigned u; } c; c.f = f;
    unsigned u = c.u + 0x7fffu + ((c.u >> 16) & 1u);
    return (unsigned short)(u >> 16);
}
__device__ __forceinline__ float lo_bf(unsigned u) {
    union { float f; unsigned u; } c; c.u = u << 16; return c.f;
}
__device__ __forceinline__ float hi_bf(unsigned u) {
    union { float f; unsigned u; } c; c.u = u & 0xffff0000u; return c.f;
}

// ---------------- diagnostics ----------------
__global__ __launch_bounds__(256) void k_constf(float* __restrict__ out, int n, float v) {
    int i = blockIdx.x * 256 + threadIdx.x;
    if (i < n) out[i] = v;
}

// ---------------- CSR build ----------------
__global__ __launch_bounds__(256) void k_count(const int* __restrict__ dst, int* __restrict__ counts) {
    int r = blockIdx.y;
    int i = blockIdx.x * 256 + threadIdx.x;
    if (i < NEDGE) {
        int d = dst[r * NEDGE + i];
        if ((unsigned)d < NN) atomicAdd(&counts[r * NN + d], 1);
    }
}

__global__ __launch_bounds__(256) void k_s1(const int* __restrict__ counts, int* __restrict__ bsum) {
    int r = blockIdx.y, b = blockIdx.x;
    int i = b * 256 + threadIdx.x;
    int v = (i < NN) ? counts[r * NN + i] : 0;
    #pragma unroll
    for (int m = 1; m < 64; m <<= 1) v += __shfl_xor(v, m);
    __shared__ int ws[4];
    int wid = threadIdx.x >> 6, lane = threadIdx.x & 63;
    if (lane == 0) ws[wid] = v;
    __syncthreads();
    if (threadIdx.x == 0) bsum[r * SNB + b] = ws[0] + ws[1] + ws[2] + ws[3];
}

__global__ __launch_bounds__(256) void k_s2(const int* __restrict__ bsum, int* __restrict__ boff) {
    int r = threadIdx.x >> 6;
    int lane = threadIdx.x & 63;
    int carry = 0;
    for (int c0 = 0; c0 < SNB; c0 += 64) {
        int b = c0 + lane;
        int v = (b < SNB) ? bsum[r * SNB + b] : 0;
        int inc = v;
        #pragma unroll
        for (int d = 1; d < 64; d <<= 1) {
            int t = __shfl_up(inc, d);
            if (lane >= d) inc += t;
        }
        if (b < SNB) boff[r * SNB + b] = carry + inc - v;
        carry += __shfl(inc, 63);
    }
}

// writes row_ptr AND initializes nxt (copynext folded in)
__global__ __launch_bounds__(256) void k_s3(const int* __restrict__ counts, const int* __restrict__ boff,
                                            int* __restrict__ row_ptr, int* __restrict__ nxt) {
    int r = blockIdx.y, b = blockIdx.x;
    int i = b * 256 + threadIdx.x;
    int v = (i < NN) ? counts[r * NN + i] : 0;
    int lane = threadIdx.x & 63, wid = threadIdx.x >> 6;
    int inc = v;
    #pragma unroll
    for (int d = 1; d < 64; d <<= 1) {
        int t = __shfl_up(inc, d);
        if (lane >= d) inc += t;
    }
    __shared__ int ws[4];
    if (lane == 63) ws[wid] = inc;
    __syncthreads();
    int woff = 0;
    #pragma unroll
    for (int w = 0; w < 4; ++w) woff += (w < wid) ? ws[w] : 0;
    if (i < NN) {
        int ex = boff[r * SNB + b] + woff + inc - v;
        row_ptr[r * (NN + 1) + i] = ex;
        nxt[r * NN + i] = ex;
    }
    if (b == 0 && threadIdx.x == 0) row_ptr[r * (NN + 1) + NN] = NEDGE;
}

__global__ __launch_bounds__(256) void k_fill(const int* __restrict__ src, const int* __restrict__ dst,
                                              int* __restrict__ nxt, int* __restrict__ csr) {
    int r = blockIdx.y;
    int i = blockIdx.x * 256 + threadIdx.x;
    if (i < NEDGE) {
        int d = dst[r * NEDGE + i];
        if ((unsigned)d >= NN) return;
        int pos = atomicAdd(&nxt[r * NN + d], 1);
        if ((unsigned)pos < NEDGE) csr[r * NEDGE + pos] = src[r * NEDGE + i];
    }
}

// ---------------- prep: wfrag + wl + wr + combined bias + h->bf16 ----------------
// per layer: 256 wfrag blocks + 128 wl blocks + 128 wr blocks = 512
__global__ __launch_bounds__(256) void k_prep(const float* __restrict__ Wsrc,
                                              const float* __restrict__ Wdst,
                                              const float* __restrict__ al,
                                              const float* __restrict__ ar,
                                              const float* __restrict__ ntb,
                                              const float* __restrict__ gb,
                                              const float* __restrict__ x,
                                              unsigned short* __restrict__ wf,
                                              float* __restrict__ wl,
                                              float* __restrict__ wr,
                                              float* __restrict__ biasc,
                                              unsigned short* __restrict__ xb) {
    int b = blockIdx.x;
    const int PL = NLAYER * 512;
    if (b < PL) {
        int l = b / 512;
        int t = b % 512;
        if (t < 256) {
            int idx = t * 256 + threadIdx.x;  // 0..65535
            int jj = idx & 7, lane = (idx >> 3) & 63, s = (idx >> 9) & 3, tt = (idx >> 11) & 7, r = idx >> 14;
            int k = s * 32 + ((lane >> 4) << 3) + jj;
            int n = tt * 16 + (lane & 15);
            wf[l * 65536 + idx] = f2bf(Wsrc[((size_t)(l * NREL + r) * DIM + k) * DIM + n]);
        } else if (t < 384) {
            int gw = (t - 256) * 4 + (threadIdx.x >> 6);  // 0..511 = r*128+k
            int lane = threadIdx.x & 63;
            int r = gw >> 7, k = gw & 127;
            const float* wrow = Wsrc + (((size_t)(l * NREL + r) * DIM + k) * DIM);
            const float* arow = al + (l * NREL + r) * DIM;
            float s = wrow[lane * 2] * arow[lane * 2] + wrow[lane * 2 + 1] * arow[lane * 2 + 1];
            #pragma unroll
            for (int m = 1; m < 64; m <<= 1) s += __shfl_xor(s, m);
            if (lane == 0) wl[l * 512 + gw] = s;
        } else {
            int gw = (t - 384) * 4 + (threadIdx.x >> 6);
            int lane = threadIdx.x & 63;
            int r = gw >> 7, k = gw & 127;
            const float* wrow = Wdst + (((size_t)(l * NREL + r) * DIM + k) * DIM);
            const float* arow = ar + (l * NREL + r) * DIM;
            float s = wrow[lane * 2] * arow[lane * 2] + wrow[lane * 2 + 1] * arow[lane * 2 + 1];
            #pragma unroll
            for (int m = 1; m < 64; m <<= 1) s += __shfl_xor(s, m);
            if (lane == 0) wr[l * 512 + gw] = s;
        }
    } else if (b < PL + 2) {
        int t = (b - PL) * 256 + threadIdx.x;
        if (t < NLAYER * DIM) {
            int l = t >> 7, k = t & 127;
            float s = ntb[t];
            #pragma unroll
            for (int r = 0; r < NREL; ++r) s += gb[(l * NREL + r) * DIM + k];
            biasc[t] = s;
        }
    } else {
        int i = ((b - PL - 2) * 256 + threadIdx.x) * 4;
        f32x4 v = *(const f32x4*)(x + i);
        unsigned short o[4];
        #pragma unroll
        for (int j = 0; j < 4; ++j) o[j] = f2bf(v[j]);
        *(ushort2*)(xb + i) = make_ushort2(o[0], o[1]);
        *(ushort2*)(xb + i + 2) = make_ushort2(o[2], o[3]);
    }
}

// ---------------- el/er for layer 0 from f32 h ----------------
__global__ __launch_bounds__(256) void k_er0(const float* __restrict__ x,
                                             const float* __restrict__ wl,
                                             const float* __restrict__ wr,
                                             float* __restrict__ el,
                                             float* __restrict__ er) {
    int oct = threadIdx.x >> 3, ol = threadIdx.x & 7;
    int n = blockIdx.x * 32 + oct;
    if (n >= NN) return;
    int f0 = ol * 16;
    const float* xp = x + (size_t)n * DIM + f0;
    f32x4 xv[4];
    #pragma unroll
    for (int k = 0; k < 4; ++k) xv[k] = *(const f32x4*)(xp + 4 * k);
    #pragma unroll
    for (int r = 0; r < NREL; ++r) {
        float sl = 0.f, sr = 0.f;
        #pragma unroll
        for (int k = 0; k < 4; ++k) {
            f32x4 lv = *(const f32x4*)(wl + r * DIM + f0 + 4 * k);
            f32x4 rv = *(const f32x4*)(wr + r * DIM + f0 + 4 * k);
            sl += xv[k][0] * lv[0] + xv[k][1] * lv[1] + xv[k][2] * lv[2] + xv[k][3] * lv[3];
            sr += xv[k][0] * rv[0] + xv[k][1] * rv[1] + xv[k][2] * rv[2] + xv[k][3] * rv[3];
        }
        sl += __shfl_xor(sl, 1); sl += __shfl_xor(sl, 2); sl += __shfl_xor(sl, 4);
        sr += __shfl_xor(sr, 1); sr += __shfl_xor(sr, 2); sr += __shfl_xor(sr, 4);
        if (ol == 0) { el[r * NN + n] = sl; er[r * NN + n] = sr; }
    }
}

// ---------------- fused layer: aggregate x -> LDS A-frags -> MFMA -> LN -> el'/er' ----------------
// 256 threads, 32 nodes/block. Phase 1 = round-0 gather (16 nodes, 4 lanes/pair,
// 1-ahead prefetch) run TWICE sequentially into two LDS A row-tiles (gather is
// request-throughput-bound, so serializing passes costs ~nothing). Phase 2 loads
// each B-fragment ONCE and reuses it across both row-tiles (B L2-traffic halved
// vs 16-node blocks). Phase 3 loops 4x over 8-node groups.
__global__ __launch_bounds__(256) void k_fused(const unsigned short* __restrict__ xb,
                                               const float* __restrict__ el,
                                               const float* __restrict__ er,
                                               const int* __restrict__ row_ptr,
                                               const int* __restrict__ csr,
                                               const unsigned short* __restrict__ wf,
                                               const float* __restrict__ biasc,
                                               const float* __restrict__ lng,
                                               const float* __restrict__ lnb,
                                               const float* __restrict__ wl,
                                               const float* __restrict__ wr,
                                               float* __restrict__ dout,
                                               unsigned short* __restrict__ xb2,
                                               float* __restrict__ el2,
                                               float* __restrict__ er2,
                                               int l, int last) {
    __shared__ s16x8 lds_a[2 * 16 * 64];   // 32KB: two 16-row A-tiles; reused as float C[32][128]
    int tid = threadIdx.x;

    // ---- phase 1: attention-weighted aggregation of x (bf16), two 16-node passes ----
    for (int p = 0; p < 2; ++p) {
        int pair = tid >> 2;        // 0..63
        int ol   = tid & 3;         // lane in pair
        int nd   = pair >> 2;       // 0..15
        int r    = pair & 3;
        int n    = blockIdx.x * NODES_PER_BLK + p * 16 + nd;
        int f0   = ol * 32;

        int valid = (n < NN);
        int nc = valid ? n : 0;
        int start = row_ptr[r * (NN + 1) + nc];
        int end   = valid ? row_ptr[r * (NN + 1) + nc + 1] : start;
        if (start < 0) start = 0;
        if (end > NEDGE) end = NEDGE;
        int deg = end - start;

        float ern = er[r * NN + nc];
        const int* cp = csr + r * NEDGE;
        const float* elp = el + r * NN;

        f32x4 av[8] = {{0,0,0,0},{0,0,0,0},{0,0,0,0},{0,0,0,0},
                       {0,0,0,0},{0,0,0,0},{0,0,0,0},{0,0,0,0}};
        float denom = 0.f;
        if (deg > 0) {
            int s0 = cp[start]; if ((unsigned)s0 >= NN) s0 = 0;
            float e0 = elp[s0];
            const uint4* hp = (const uint4*)(xb + (size_t)s0 * DIM + f0);
            uint4 xa = hp[0], xbv = hp[1], xc = hp[2], xd = hp[3];
            for (int e = 0; e < deg; ++e) {
                int i1 = start + e + 1; i1 = (i1 < end) ? i1 : start;
                int s1 = cp[i1]; if ((unsigned)s1 >= NN) s1 = 0;
                float e1 = elp[s1];
                const uint4* hp1 = (const uint4*)(xb + (size_t)s1 * DIM + f0);
                uint4 ya = hp1[0], yb = hp1[1], yc = hp1[2], yd = hp1[3];

                float ev = e0 + ern;
                ev = ev >= 0.f ? ev : 0.2f * ev;
                ev = fminf(fmaxf(ev, -60.f), 60.f);
                float pw = __expf(ev);
                denom += pw;
                av[0][0] += pw * lo_bf(xa.x); av[0][1] += pw * hi_bf(xa.x);
                av[0][2] += pw * lo_bf(xa.y); av[0][3] += pw * hi_bf(xa.y);
                av[1][0] += pw * lo_bf(xa.z); av[1][1] += pw * hi_bf(xa.z);
                av[1][2] += pw * lo_bf(xa.w); av[1][3] += pw * hi_bf(xa.w);
                av[2][0] += pw * lo_bf(xbv.x); av[2][1] += pw * hi_bf(xbv.x);
                av[2][2] += pw * lo_bf(xbv.y); av[2][3] += pw * hi_bf(xbv.y);
                av[3][0] += pw * lo_bf(xbv.z); av[3][1] += pw * hi_bf(xbv.z);
                av[3][2] += pw * lo_bf(xbv.w); av[3][3] += pw * hi_bf(xbv.w);
                av[4][0] += pw * lo_bf(xc.x); av[4][1] += pw * hi_bf(xc.x);
                av[4][2] += pw * lo_bf(xc.y); av[4][3] += pw * hi_bf(xc.y);
                av[5][0] += pw * lo_bf(xc.z); av[5][1] += pw * hi_bf(xc.z);
                av[5][2] += pw * lo_bf(xc.w); av[5][3] += pw * hi_bf(xc.w);
                av[6][0] += pw * lo_bf(xd.x); av[6][1] += pw * hi_bf(xd.x);
                av[6][2] += pw * lo_bf(xd.y); av[6][3] += pw * hi_bf(xd.y);
                av[7][0] += pw * lo_bf(xd.z); av[7][1] += pw * hi_bf(xd.z);
                av[7][2] += pw * lo_bf(xd.w); av[7][3] += pw * hi_bf(xd.w);
                e0 = e1; xa = ya; xbv = yb; xc = yc; xd = yd;
            }
        }
        float inv = (deg > 0) ? (1.0f / denom) : 0.f;
        // pack to bf16 A-frags: lane covers k = r*128 + ol*32 + [0,32)
        #pragma unroll
        for (int q = 0; q < 4; ++q) {
            s16x8 o;
            #pragma unroll
            for (int j = 0; j < 4; ++j) {
                o[j]     = (short)f2bf(av[2 * q][j] * inv);
                o[j + 4] = (short)f2bf(av[2 * q + 1][j] * inv);
            }
            lds_a[p * 1024 + (r * 4 + ol) * 64 + q * 16 + nd] = o;
        }
    }
    __syncthreads();

    // ---- phase 2: C[32x128] = A[32x512] @ W[512x128]; 4 waves x 2 col-tiles,
    //      B-frags loaded once and reused across both row-tiles ----
    int wv = tid >> 6, lane = tid & 63;
    int quad = lane >> 4, n16 = lane & 15;
    f32x4 acc00 = {0.f, 0.f, 0.f, 0.f}, acc01 = {0.f, 0.f, 0.f, 0.f};
    f32x4 acc10 = {0.f, 0.f, 0.f, 0.f}, acc11 = {0.f, 0.f, 0.f, 0.f};
    {
        const s16x8* wfp = (const s16x8*)wf + (size_t)l * NREL * 2048;
        int t0c = wv * 2, t1c = wv * 2 + 1;
        #pragma unroll
        for (int sp = 0; sp < 16; ++sp) {
            s16x8 a0 = lds_a[sp * 64 + lane];
            s16x8 a1 = lds_a[1024 + sp * 64 + lane];
            const s16x8* wb = wfp + (size_t)(sp >> 2) * 2048;
            int sl = sp & 3;
            s16x8 b0 = wb[(t0c * 4 + sl) * 64 + lane];
            s16x8 b1 = wb[(t1c * 4 + sl) * 64 + lane];
            acc00 = __builtin_amdgcn_mfma_f32_16x16x32_bf16(a0, b0, acc00, 0, 0, 0);
            acc01 = __builtin_amdgcn_mfma_f32_16x16x32_bf16(a0, b1, acc01, 0, 0, 0);
            acc10 = __builtin_amdgcn_mfma_f32_16x16x32_bf16(a1, b0, acc10, 0, 0, 0);
            acc11 = __builtin_amdgcn_mfma_f32_16x16x32_bf16(a1, b1, acc11, 0, 0, 0);
        }
    }
    __syncthreads();
    float* Cl = (float*)lds_a;
    {
        int t0c = wv * 2, t1c = wv * 2 + 1;
        #pragma unroll
        for (int reg = 0; reg < 4; ++reg) {
            int row = quad * 4 + reg;
            Cl[row * DIM + t0c * 16 + n16] = acc00[reg];
            Cl[row * DIM + t1c * 16 + n16] = acc01[reg];
            Cl[(16 + row) * DIM + t0c * 16 + n16] = acc10[reg];
            Cl[(16 + row) * DIM + t1c * 16 + n16] = acc11[reg];
        }
    }
    __syncthreads();

    // ---- phase 3: bias + ReLU + LayerNorm + outputs + next-layer el'/er' (4 x 8 nodes) ----
    for (int it = 0; it < 4; ++it) {
        int nd2 = it * 8 + (tid >> 5);   // 0..31
        int sub = tid & 31;
        int f   = sub * 4;
        int n2  = blockIdx.x * NODES_PER_BLK + nd2;
        if (n2 >= NN) continue;

        float t[4];
        #pragma unroll
        for (int j = 0; j < 4; ++j) t[j] = Cl[nd2 * DIM + f + j] + biasc[l * DIM + f + j];
        if (!last) {
            #pragma unroll
            for (int j = 0; j < 4; ++j) t[j] = fmaxf(t[j], 0.f);
        }
        float s1 = 0.f;
        #pragma unroll
        for (int j = 0; j < 4; ++j) s1 += t[j];
        s1 += __shfl_xor(s1, 1); s1 += __shfl_xor(s1, 2);
        s1 += __shfl_xor(s1, 4); s1 += __shfl_xor(s1, 8);
        s1 += __shfl_xor(s1, 16);
        float mean = s1 * (1.0f / 128.0f);
        float s2 = 0.f;
        #pragma unroll
        for (int j = 0; j < 4; ++j) { t[j] -= mean; s2 += t[j] * t[j]; }
        s2 += __shfl_xor(s2, 1); s2 += __shfl_xor(s2, 2);
        s2 += __shfl_xor(s2, 4); s2 += __shfl_xor(s2, 8);
        s2 += __shfl_xor(s2, 16);
        float rs = rsqrtf(s2 * (1.0f / 128.0f) + 1e-5f);

        float y[4];
        #pragma unroll
        for (int j = 0; j < 4; ++j)
            y[j] = t[j] * rs * lng[l * DIM + f + j] + lnb[l * DIM + f + j];

        if (last) {
            float* op = dout + (size_t)n2 * DIM + f;
            f32x4 v0;
            v0[0] = y[0]; v0[1] = y[1]; v0[2] = y[2]; v0[3] = y[3];
            *(f32x4*)op = v0;
        } else {
            unsigned pk0 = (unsigned)f2bf(y[0]) | ((unsigned)f2bf(y[1]) << 16);
            unsigned pk1 = (unsigned)f2bf(y[2]) | ((unsigned)f2bf(y[3]) << 16);
            uint2 v; v.x = pk0; v.y = pk1;
            *(uint2*)(xb2 + (size_t)n2 * DIM + f) = v;

            const float* wlp = wl + (l + 1) * 512;
            const float* wrp = wr + (l + 1) * 512;
            #pragma unroll
            for (int rp = 0; rp < NREL; ++rp) {
                float sl_ = 0.f, sr_ = 0.f;
                #pragma unroll
                for (int j = 0; j < 4; ++j) {
                    sl_ += y[j] * wlp[rp * DIM + f + j];
                    sr_ += y[j] * wrp[rp * DIM + f + j];
                }
                sl_ += __shfl_xor(sl_, 1); sl_ += __shfl_xor(sl_, 2);
                sl_ += __shfl_xor(sl_, 4); sl_ += __shfl_xor(sl_, 8);
                sl_ += __shfl_xor(sl_, 16);
                sr_ += __shfl_xor(sr_, 1); sr_ += __shfl_xor(sr_, 2);
                sr_ += __shfl_xor(sr_, 4); sr_ += __shfl_xor(sr_, 8);
                sr_ += __shfl_xor(sr_, 16);
                if (sub == 0) {
                    el2[rp * NN + n2] = sl_;
                    er2[rp * NN + n2] = sr_;
                }
            }
        }
    }
}

extern "C" void kernel_launch(void* const* d_in, const int* in_sizes, int n_in,
                              void* d_out, int out_size, void* d_ws, size_t ws_size,
                              hipStream_t stream) {
    const float* h        = (const float*)d_in[0];
    const int*   edge_src = (const int*)d_in[1];
    const int*   edge_dst = (const int*)d_in[2];
    const float* W_src    = (const float*)d_in[3];
    const float* W_dst    = (const float*)d_in[4];
    const float* attn_l   = (const float*)d_in[5];
    const float* attn_r   = (const float*)d_in[6];
    const float* gat_bias = (const float*)d_in[7];
    const float* ntype_b  = (const float*)d_in[8];
    const float* ln_g     = (const float*)d_in[9];
    const float* ln_b     = (const float*)d_in[10];

    if (n_in < 11) return;
    if (in_sizes[0] != NN * DIM) return;
    if (in_sizes[1] != NREL * NEDGE || in_sizes[2] != NREL * NEDGE) return;
    if (in_sizes[3] != NLAYER * NREL * DIM * DIM || in_sizes[4] != NLAYER * NREL * DIM * DIM) return;
    if (in_sizes[5] != NLAYER * NREL * DIM || in_sizes[6] != NLAYER * NREL * DIM) return;
    if (in_sizes[7] != NLAYER * NREL * DIM || in_sizes[8] != NLAYER * DIM) return;
    if (out_size != NN * DIM) return;

    auto align256 = [](size_t x) { return (x + 255) & ~(size_t)255; };
    size_t szElEr = align256((size_t)NREL * NN * 4);            // x4 buffers
    size_t szXbf  = align256((size_t)NN * DIM * 2);             // x2 buffers
    size_t szWlr  = align256((size_t)NLAYER * 512 * 4);         // x2
    size_t szBc   = align256((size_t)NLAYER * DIM * 4);
    size_t szWf   = align256((size_t)NLAYER * NREL * DIM * DIM * 2);
    size_t szRp   = align256((size_t)NREL * (NN + 1) * 4);
    size_t szNxt  = align256((size_t)NREL * NN * 4);
    size_t szCsr  = align256((size_t)NREL * NEDGE * 4);
    size_t szScn  = align256((size_t)NREL * SNB * 4) * 2;
    size_t need = 4 * szElEr + 2 * szXbf + 2 * szWlr + szBc + szWf + szRp + szNxt + szCsr + szScn;

    if (ws_size < need) {
        k_constf<<<(NN * DIM + 255) / 256, 256, 0, stream>>>((float*)d_out, NN * DIM, 100.0f);
        return;
    }

    char* base = (char*)d_ws;
    size_t off = 0;
    auto alloc = [&](size_t bytes) -> char* { char* p = base + off; off += align256(bytes); return p; };

    float* el   = (float*)alloc((size_t)NREL * NN * 4);
    float* er   = (float*)alloc((size_t)NREL * NN * 4);
    float* el2  = (float*)alloc((size_t)NREL * NN * 4);
    float* er2  = (float*)alloc((size_t)NREL * NN * 4);
    unsigned short* xbf  = (unsigned short*)alloc((size_t)NN * DIM * 2);
    unsigned short* xbf2 = (unsigned short*)alloc((size_t)NN * DIM * 2);
    float* wl    = (float*)alloc((size_t)NLAYER * 512 * 4);
    float* wr    = (float*)alloc((size_t)NLAYER * 512 * 4);
    float* biasc = (float*)alloc((size_t)NLAYER * DIM * 4);
    unsigned short* wfrag = (unsigned short*)alloc((size_t)NLAYER * NREL * DIM * DIM * 2);
    int* rowp = (int*)alloc((size_t)NREL * (NN + 1) * 4);
    int* nxt  = (int*)alloc((size_t)NREL * NN * 4);
    int* csr  = (int*)alloc((size_t)NREL * NEDGE * 4);
    int* bsum = (int*)alloc((size_t)NREL * SNB * 4);
    int* boff = (int*)alloc((size_t)NREL * SNB * 4);

    // ---- CSR build + prep + layer-0 el/er ----
    (void)hipMemsetAsync(nxt, 0, (size_t)NREL * NN * 4, stream);
    k_count<<<dim3((NEDGE + 255) / 256, NREL), 256, 0, stream>>>(edge_dst, nxt);
    k_s1<<<dim3(SNB, NREL), 256, 0, stream>>>(nxt, bsum);
    k_s2<<<1, 256, 0, stream>>>(bsum, boff);
    k_s3<<<dim3(SNB, NREL), 256, 0, stream>>>(nxt, boff, rowp, nxt);
    k_fill<<<dim3((NEDGE + 255) / 256, NREL), 256, 0, stream>>>(edge_src, edge_dst, nxt, csr);
    k_prep<<<NLAYER * 512 + 2 + NN * DIM / 1024, 256, 0, stream>>>(
        W_src, W_dst, attn_l, attn_r, ntype_b, gat_bias, h, wfrag, wl, wr, biasc, xbf);
    k_er0<<<(NN + 31) / 32, 256, 0, stream>>>(h, wl, wr, el, er);

    // ---- layers (ping-pong xbf / el / er) ----
    float* dout = (float*)d_out;
    int nblk = (NN + NODES_PER_BLK - 1) / NODES_PER_BLK;
    // l = 0: in (xbf, el, er) -> out (xbf2, el2, er2)
    k_fused<<<nblk, 256, 0, stream>>>(xbf, el, er, rowp, csr, wfrag, biasc, ln_g, ln_b,
                                      wl, wr, dout, xbf2, el2, er2, 0, 0);
    // l = 1: in (xbf2, el2, er2) -> out (xbf, el, er)
    k_fused<<<nblk, 256, 0, stream>>>(xbf2, el2, er2, rowp, csr, wfrag, biasc, ln_g, ln_b,
                                      wl, wr, dout, xbf, el, er, 1, 0);
    // l = 2 (last): in (xbf, el, er) -> d_out
    k_fused<<<nblk, 256, 0, stream>>>(xbf, el, er, rowp, csr, wfrag, biasc, ln_g, ln_b,
                                      wl, wr, dout, xbf2, el2, er2, 2, 1);
}